// Round 18
// baseline (138.480 us; speedup 1.0000x reference)
//
#include <hip/hip_runtime.h>
#include <hip/hip_bf16.h>

#define TSEQ 2048
#define DM   1024
#define NH   16
#define HDIM 64
#define NB   2
#define BT   (NB*TSEQ)   // 4096
// Q pre-scale: HD^-0.5 * log2(e) so softmax runs in exp2 domain
#define QSCALE 0.1803368801111204f

typedef __attribute__((ext_vector_type(8))) short bf16x8;
typedef __attribute__((ext_vector_type(4))) float f32x4;

static __device__ __forceinline__ ushort f2b(float x) {
    unsigned u = __float_as_uint(x);
    return (ushort)((u + 0x7fff + ((u >> 16) & 1)) >> 16);  // RNE, finite inputs
}

static __device__ __forceinline__ unsigned cvtpk(float lo, float hi) {
    unsigned r;
    asm("v_cvt_pk_bf16_f32 %0, %1, %2" : "=v"(r) : "v"(lo), "v"(hi));
    return r;
}

static __device__ __forceinline__ float fmax3(float a, float b, float c) {
    return fmaxf(fmaxf(a, b), c);   // clang fuses to v_max3_f32
}

static __device__ __forceinline__ void gload16(const void* g, void* l) {
    __builtin_amdgcn_global_load_lds((const __attribute__((address_space(1))) void*)g,
                                     (__attribute__((address_space(3))) void*)l, 16, 0, 0);
}

// ---------------------------------------------------------------------------
// Merged prep: [0,2048) cvt x -> bf16; [2048,2560) cvt Wp -> bf16;
// [2560,3328) per-head weight transpose f32 [D][HD] -> bf16 [mat][h][e][D].
// ---------------------------------------------------------------------------
__global__ __launch_bounds__(256) void prep_kernel(const float* __restrict__ x,
                                                   const float* __restrict__ Wq,
                                                   const float* __restrict__ Wk,
                                                   const float* __restrict__ Wv,
                                                   const float* __restrict__ Wp,
                                                   ushort* __restrict__ xb,
                                                   ushort* __restrict__ wpb,
                                                   ushort* __restrict__ wtb) {
    __shared__ float tile[64][65];
    const int g = blockIdx.x, t = threadIdx.x;
    if (g < 2560) {
        const float* src = (g < 2048) ? x : Wp;
        ushort* dst = (g < 2048) ? xb : wpb;
        int i = ((g < 2048) ? g : (g - 2048)) * 256 + t;
        const float4* s = reinterpret_cast<const float4*>(src);
        float4 a = s[2*i], b = s[2*i+1];
        union { ushort u[8]; int4 v; } r;
        r.u[0]=f2b(a.x); r.u[1]=f2b(a.y); r.u[2]=f2b(a.z); r.u[3]=f2b(a.w);
        r.u[4]=f2b(b.x); r.u[5]=f2b(b.y); r.u[6]=f2b(b.z); r.u[7]=f2b(b.w);
        reinterpret_cast<int4*>(dst)[i] = r.v;
        return;
    }
    const int gb = g - 2560;
    const int k0 = (gb & 15) * 64;
    const int math = gb >> 4;               // 0..47
    const int mat = math >> 4, h = math & 15;
    const float* W = (mat == 0 ? Wq : (mat == 1 ? Wk : Wv)) + (size_t)h * DM * HDIM;
#pragma unroll
    for (int it = 0; it < 4; ++it) {
        int row = it*16 + (t>>4), c4 = (t&15)*4;
        float4 v = *reinterpret_cast<const float4*>(&W[(size_t)(k0+row)*HDIM + c4]);
        tile[row][c4+0]=v.x; tile[row][c4+1]=v.y; tile[row][c4+2]=v.z; tile[row][c4+3]=v.w;
    }
    __syncthreads();
    ushort* out = wtb + (size_t)(mat*NH + h) * (HDIM*DM);
#pragma unroll
    for (int it = 0; it < 4; ++it) {
        int n = it*16 + (t>>4), kc = (t&15)*4;
        union { ushort u[4]; uint2 v; } r;
#pragma unroll
        for (int j = 0; j < 4; ++j) r.u[j] = f2b(tile[kc+j][n]);
        *reinterpret_cast<uint2*>(&out[(size_t)n*DM + k0 + kc]) = r.v;
    }
}

// ---------------------------------------------------------------------------
// m97-style GEMM: C[M][N] = A[M][1024] @ B[N][1024]^T
// 128x128 tile, BK=64, 4 waves, global_load_lds w16, XCD-chunked swizzle.
// EPI 0: qk scatter (bf16, QSCALE on mat 0), row-major [bh][t][e]. N=2048.
// EPI 1: proj (f32 + bias).
// EPI 2: v^T [bh][e][t] via LDS-transpose epilogue: acc holds 4 consecutive t
//        at fixed e -> b64 LDS writes into CT[e][t] (XOR-swizzled), barrier,
//        read back 16B chunks -> 256B-contiguous coalesced global stores.
// ---------------------------------------------------------------------------
template<int EPI>
__global__ __launch_bounds__(256) void gemm_bt(const ushort* __restrict__ A,
                                               const ushort* __restrict__ B,
                                               const float* __restrict__ bias,
                                               void* __restrict__ C) {
    __shared__ ushort As[128*64];
    __shared__ ushort Bs[128*64];
    const int tid = threadIdx.x;
    const int w = tid >> 6, l = tid & 63;
    const int lr = l & 15, lg = l >> 4;
    const int wr = (w >> 1) * 64, wc = (w & 1) * 64;
    const int cpx = (int)gridDim.x >> 3;
    const int wg = ((int)blockIdx.x & 7) * cpx + ((int)blockIdx.x >> 3);
    const int m0 = (wg & 31) * 128;
    const int n0 = (wg >> 5) * 128;
    const int srow = l >> 3;
    const int scol = (l & 7) * 8;

    f32x4 acc[4][4];
#pragma unroll
    for (int a = 0; a < 4; ++a)
#pragma unroll
        for (int b = 0; b < 4; ++b) acc[a][b] = {0.f, 0.f, 0.f, 0.f};

    for (int kc = 0; kc < DM/64; ++kc) {
        __syncthreads();
#pragma unroll
        for (int c = 0; c < 4; ++c) {
            int chunk = w*4 + c;
            int r = chunk*8 + srow;
            gload16(&A[(size_t)(m0+r)*DM + kc*64 + scol], &As[chunk*512]);
            gload16(&B[(size_t)(n0+r)*DM + kc*64 + scol], &Bs[chunk*512]);
        }
        __syncthreads();
#pragma unroll
        for (int kk = 0; kk < 2; ++kk) {
            bf16x8 af[4], bf[4];
#pragma unroll
            for (int mf = 0; mf < 4; ++mf)
                af[mf] = *reinterpret_cast<const bf16x8*>(&As[(wr + mf*16 + lr)*64 + kk*32 + lg*8]);
#pragma unroll
            for (int nf = 0; nf < 4; ++nf)
                bf[nf] = *reinterpret_cast<const bf16x8*>(&Bs[(wc + nf*16 + lr)*64 + kk*32 + lg*8]);
            __builtin_amdgcn_s_setprio(1);
#pragma unroll
            for (int mf = 0; mf < 4; ++mf)
#pragma unroll
                for (int nf = 0; nf < 4; ++nf)
                    acc[mf][nf] = __builtin_amdgcn_mfma_f32_16x16x32_bf16(
                        af[mf], bf[nf], acc[mf][nf], 0, 0, 0);
            __builtin_amdgcn_s_setprio(0);
        }
    }

    if (EPI == 0) {
        ushort* O = (ushort*)C;
#pragma unroll
        for (int mf = 0; mf < 4; ++mf) {
#pragma unroll
            for (int i = 0; i < 4; ++i) {
                int m = m0 + wr + mf*16 + lg*4 + i;
                int bq = m >> 11, t = m & (TSEQ - 1);
#pragma unroll
                for (int nf = 0; nf < 4; ++nf) {
                    int col = n0 + wc + nf*16 + lr;
                    int mat = col >> 10, hh = (col >> 6) & 15, e = col & 63;
                    float sc = (mat == 0) ? QSCALE : 1.0f;
                    O[((size_t)(mat*2*NH + bq*NH + hh))*(TSEQ*HDIM) + (size_t)t*HDIM + e] =
                        f2b(acc[mf][nf][i] * sc);
                }
            }
        }
    } else if (EPI == 2) {
        // transpose through LDS: CT[e_local][t_local], chunk-swizzled
        __shared__ ushort CT[128*128];
        __syncthreads();
#pragma unroll
        for (int mf = 0; mf < 4; ++mf) {
            int t_l = wr + mf*16 + lg*4;            // 4 consecutive t
#pragma unroll
            for (int nf = 0; nf < 4; ++nf) {
                int e_l = wc + nf*16 + lr;
                uint2 pk;
                pk.x = cvtpk(acc[mf][nf][0], acc[mf][nf][1]);
                pk.y = cvtpk(acc[mf][nf][2], acc[mf][nf][3]);
                *reinterpret_cast<uint2*>(&CT[e_l*128 + (t_l ^ ((e_l & 7) << 3))]) = pk;
            }
        }
        __syncthreads();
        ushort* O = (ushort*)C;
#pragma unroll
        for (int it = 0; it < 8; ++it) {
            int slot = it*256 + tid;                // 0..2047
            int row = slot >> 4;                    // e_local
            int chunk = slot & 15;                  // 16B chunk of t
            int n = n0 + row, hh = n >> 6, e = n & 63;
            int tglob = m0 + chunk*8;
            int bq = tglob >> 11, tt = tglob & (TSEQ - 1);
            *reinterpret_cast<int4*>(
                &O[((size_t)(4*NH + bq*NH + hh))*(TSEQ*HDIM) + (size_t)e*TSEQ + tt]) =
                *reinterpret_cast<const int4*>(&CT[row*128 + ((chunk ^ (row & 7))*8)]);
        }
    } else {
        float* O = (float*)C;
#pragma unroll
        for (int mf = 0; mf < 4; ++mf) {
#pragma unroll
            for (int i = 0; i < 4; ++i) {
                int m = m0 + wr + mf*16 + lg*4 + i;
#pragma unroll
                for (int nf = 0; nf < 4; ++nf) {
                    int col = n0 + wc + nf*16 + lr;
                    O[(size_t)m*DM + col] = acc[mf][nf][i] + bias[col];
                }
            }
        }
    }
}

// ---------------------------------------------------------------------------
// Causal flash attention, paired q-tiles, 8-wave blocks. 512 blocks x 512 thr.
// Block (bh,p): q-tiles 16+p (waves 0-3), 15-p (waves 4-7); K row-major AND
// V^T row-major [e][t] BOTH staged via global_load_lds DMA with XOR
// pre-swizzled source -> zero-VALU staging. Softmax: per-lane partial l
// (reduced once at epilogue) + lazy cross-lane max. P: cvt_pk -> per-wave LDS.
// ---------------------------------------------------------------------------
__global__ __launch_bounds__(512) void attn_mfma(const ushort* __restrict__ qkvb,
                                                 ushort* __restrict__ concatb) {
    __shared__ ushort Ks[2][64*64];
    __shared__ ushort Vt[2][64*64];     // [e][s], swizzled (DMA'd from v^T)
    __shared__ ushort Ps[8][16*64];     // per-wave P^T (16 q-rows)
    const int tid = threadIdx.x;
    const int w = tid >> 6, l = tid & 63;
    const int lr = l & 15, lg = l >> 4;
    const int g = blockIdx.x;
    const int bh = (g & 7) * 4 + ((g >> 3) & 3);   // 4 heads per XCD
    const int p  = g >> 5;                          // pair index 0..15
    const int qtHI = 16 + p, qtLO = 15 - p;
    const int sub = w >> 2;                         // 0 = HI wave, 1 = LO wave
    const int ws  = w & 3;
    const int myqt = sub ? qtLO : qtHI;
    const int q0 = myqt * 64 + ws * 16;             // wave's 16 q-rows

    const ushort* Q  = qkvb + (size_t)bh * (TSEQ*HDIM);
    const ushort* K  = Q + (size_t)2*NH*TSEQ*HDIM;
    const ushort* VT = K + (size_t)2*NH*TSEQ*HDIM;  // [e][t], rows of TSEQ

    bf16x8 qf[2];
#pragma unroll
    for (int kk = 0; kk < 2; ++kk)
        qf[kk] = *reinterpret_cast<const bf16x8*>(&Q[(size_t)(q0 + lr)*HDIM + kk*32 + lg*8]);

    f32x4 acc[4];
    float mrow = -3e38f, lrow = 0.f;                // lrow = per-lane partial
#pragma unroll
    for (int nf = 0; nf < 4; ++nf) acc[nf] = {0.f, 0.f, 0.f, 0.f};

    ushort* PsW = &Ps[w][0];
    const int krow = tid >> 3;                      // 0..63 over 512 threads
    const int kchunk = (tid & 7) ^ ((tid >> 3) & 7);

    // ---- prologue: stage tile 0 into buf 0 (all DMA) ----
    {
        gload16(&K [(size_t)krow*HDIM + kchunk*8], &Ks[0][tid*8]);
        gload16(&VT[(size_t)krow*TSEQ + kchunk*8], &Vt[0][tid*8]);
        __syncthreads();
    }

    int cur = 0;
    for (int jt = 0; jt <= qtHI; ++jt) {
        const int nxt = cur ^ 1;
        const int s0 = jt * 64;
        const bool pref = (jt < qtHI);
        const bool active = (sub == 0) || (jt <= qtLO);
        if (pref) {
            const int s0n = s0 + 64;
            gload16(&K [(size_t)(s0n + krow)*HDIM + kchunk*8], &Ks[nxt][tid*8]);
            gload16(&VT[(size_t)krow*TSEQ + s0n + kchunk*8], &Vt[nxt][tid*8]);
        }

        if (active) {
            // ---- QK^T ----
            f32x4 sT[4];
#pragma unroll
            for (int nf = 0; nf < 4; ++nf) sT[nf] = {0.f, 0.f, 0.f, 0.f};
#pragma unroll
            for (int kk = 0; kk < 2; ++kk) {
                bf16x8 kf[4];
#pragma unroll
                for (int nf = 0; nf < 4; ++nf)
                    kf[nf] = *reinterpret_cast<const bf16x8*>(
                        &Ks[cur][(nf*16 + lr)*64 + ((kk*4 + lg) ^ (lr&7))*8]);
                __builtin_amdgcn_s_setprio(1);
#pragma unroll
                for (int nf = 0; nf < 4; ++nf)
                    sT[nf] = __builtin_amdgcn_mfma_f32_16x16x32_bf16(kf[nf], qf[kk], sT[nf], 0, 0, 0);
                __builtin_amdgcn_s_setprio(0);
            }
            // causal mask on own diagonal tile
            if (jt == myqt) {
                int qrow = q0 + lr;
#pragma unroll
                for (int nf = 0; nf < 4; ++nf) {
                    int kbase = s0 + nf*16 + lg*4;
#pragma unroll
                    for (int i = 0; i < 4; ++i)
                        if (kbase + i > qrow) sT[nf][i] = -1e30f;
                }
            }
            // ---- per-lane online softmax; lazy cross-lane max; no sum shfl ----
            float g0 = fmax3(sT[0][0], sT[0][1], sT[0][2]);
            float g1 = fmax3(sT[0][3], sT[1][0], sT[1][1]);
            float g2 = fmax3(sT[1][2], sT[1][3], sT[2][0]);
            float g3 = fmax3(sT[2][1], sT[2][2], sT[2][3]);
            float g4 = fmax3(sT[3][0], sT[3][1], sT[3][2]);
            float tm = fmaxf(fmax3(fmax3(g0, g1, g2), g3, g4), sT[3][3]);
            if (__any(tm > mrow + 8.0f)) {          // rare after tile 0
                tm = fmaxf(tm, __shfl_xor(tm, 16, 64));
                tm = fmaxf(tm, __shfl_xor(tm, 32, 64));
                float mnew = fmaxf(mrow, tm);
                float corr = exp2f(mrow - mnew);
                lrow *= corr;
#pragma unroll
                for (int nf = 0; nf < 4; ++nf)
#pragma unroll
                    for (int i = 0; i < 4; ++i) acc[nf][i] *= corr;
                mrow = mnew;
            }
            float ps = 0.f;
#pragma unroll
            for (int nf = 0; nf < 4; ++nf)
#pragma unroll
                for (int i = 0; i < 4; ++i) { sT[nf][i] = exp2f(sT[nf][i] - mrow); ps += sT[nf][i]; }
            lrow += ps;                             // per-lane partial; reduce at end
            // P^T -> per-wave LDS (swizzled b64 writes)
#pragma unroll
            for (int nf = 0; nf < 4; ++nf) {
                uint2 pk;
                pk.x = cvtpk(sT[nf][0], sT[nf][1]);
                pk.y = cvtpk(sT[nf][2], sT[nf][3]);
                *reinterpret_cast<uint2*>(
                    &PsW[lr*64 + ((2*nf + (lg>>1)) ^ (lr&7))*8 + (lg&1)*4]) = pk;
            }
            // ---- PV ----
#pragma unroll
            for (int kk = 0; kk < 2; ++kk) {
                bf16x8 vf[4];
#pragma unroll
                for (int nf = 0; nf < 4; ++nf)
                    vf[nf] = *reinterpret_cast<const bf16x8*>(
                        &Vt[cur][(nf*16 + lr)*64 + ((kk*4 + lg) ^ (lr&7))*8]);
                bf16x8 pf = *reinterpret_cast<const bf16x8*>(
                    &PsW[lr*64 + ((kk*4 + lg) ^ (lr&7))*8]);
                __builtin_amdgcn_s_setprio(1);
#pragma unroll
                for (int nf = 0; nf < 4; ++nf)
                    acc[nf] = __builtin_amdgcn_mfma_f32_16x16x32_bf16(vf[nf], pf, acc[nf], 0, 0, 0);
                __builtin_amdgcn_s_setprio(0);
            }
        }

        __syncthreads();
        cur = nxt;
    }

    // ---- epilogue: reduce per-lane l across the lg group (once), write O ----
    lrow += __shfl_xor(lrow, 16, 64);
    lrow += __shfl_xor(lrow, 32, 64);
    const int b = bh >> 4, h = bh & 15;
    {
        float inv = 1.0f / lrow;
        int t = q0 + lr;
        ushort* o = concatb + ((size_t)(b*TSEQ + t))*DM + h*HDIM;
#pragma unroll
        for (int nf = 0; nf < 4; ++nf) {
            uint2 pk;
            pk.x = cvtpk(acc[nf][0]*inv, acc[nf][1]*inv);
            pk.y = cvtpk(acc[nf][2]*inv, acc[nf][3]*inv);
            *reinterpret_cast<uint2*>(&o[nf*16 + lg*4]) = pk;
        }
    }
}

// ---------------------------------------------------------------------------
extern "C" void kernel_launch(void* const* d_in, const int* in_sizes, int n_in,
                              void* d_out, int out_size, void* d_ws, size_t ws_size,
                              hipStream_t stream) {
    const float* x  = (const float*)d_in[0];
    const float* Wq = (const float*)d_in[1];
    const float* Wk = (const float*)d_in[2];
    const float* Wv = (const float*)d_in[3];
    const float* Wp = (const float*)d_in[4];
    const float* bp = (const float*)d_in[5];
    float* out = (float*)d_out;

    ushort* ws   = (ushort*)d_ws;
    ushort* xb   = ws;                                    // BT*DM
    ushort* wtb  = xb  + (size_t)BT*DM;                   // [3072][1024]
    ushort* wpb  = wtb + (size_t)3*NH*HDIM*DM;            // DM*DM
    ushort* qkvb = wpb + (size_t)DM*DM;                   // q,k: [bh][t][e]; v: [bh][e][t]
    ushort* cb   = qkvb + (size_t)3*2*NH*TSEQ*HDIM;       // BT*DM
    const ushort* wtbv = wtb + (size_t)2*NH*HDIM*DM;      // Wv rows [1024 e][1024 d]

    prep_kernel<<<dim3(3328), 256, 0, stream>>>(x, Wq, Wk, Wv, Wp, xb, wpb, wtb);
    // q,k: A=x (M=4096), B=Wq/Wk rows (N=2048)
    gemm_bt<0><<<dim3(32*16), 256, 0, stream>>>(xb, wtb, nullptr, qkvb);
    // v^T: A=x (M=4096 t), B=Wv rows (N=1024 e) -> [bh][e][t] via LDS transpose
    gemm_bt<2><<<dim3(32*8), 256, 0, stream>>>(xb, wtbv, nullptr, qkvb);
    attn_mfma<<<dim3(512), 512, 0, stream>>>(qkvb, cb);
    gemm_bt<1><<<dim3(32*8), 256, 0, stream>>>(cb, wpb, bp, out);
}

// Round 19
// 116.504 us; speedup vs baseline: 1.1886x; 1.1886x over previous
//
#include <hip/hip_runtime.h>
#include <hip/hip_bf16.h>

#define TSEQ 2048
#define DM   1024
#define NH   16
#define HDIM 64
#define NB   2
#define BT   (NB*TSEQ)   // 4096
// Q pre-scale: HD^-0.5 * log2(e) so softmax runs in exp2 domain
#define QSCALE 0.1803368801111204f

typedef __attribute__((ext_vector_type(8))) short bf16x8;
typedef __attribute__((ext_vector_type(4))) float f32x4;

union BF8 { bf16x8 v; ushort u[8]; };

static __device__ __forceinline__ ushort f2b(float x) {
    unsigned u = __float_as_uint(x);
    return (ushort)((u + 0x7fff + ((u >> 16) & 1)) >> 16);  // RNE, finite inputs
}

static __device__ __forceinline__ unsigned cvtpk(float lo, float hi) {
    unsigned r;
    asm("v_cvt_pk_bf16_f32 %0, %1, %2" : "=v"(r) : "v"(lo), "v"(hi));
    return r;
}

static __device__ __forceinline__ float fmax3(float a, float b, float c) {
    return fmaxf(fmaxf(a, b), c);   // clang fuses to v_max3_f32
}

static __device__ __forceinline__ void gload16(const void* g, void* l) {
    __builtin_amdgcn_global_load_lds((const __attribute__((address_space(1))) void*)g,
                                     (__attribute__((address_space(3))) void*)l, 16, 0, 0);
}

// ---------------------------------------------------------------------------
// Merged prep: [0,2048) cvt x -> bf16; [2048,2560) cvt Wp -> bf16;
// [2560,3328) per-head weight transpose f32 [D][HD] -> bf16 [mat][h][e][D].
// ---------------------------------------------------------------------------
__global__ __launch_bounds__(256) void prep_kernel(const float* __restrict__ x,
                                                   const float* __restrict__ Wq,
                                                   const float* __restrict__ Wk,
                                                   const float* __restrict__ Wv,
                                                   const float* __restrict__ Wp,
                                                   ushort* __restrict__ xb,
                                                   ushort* __restrict__ wpb,
                                                   ushort* __restrict__ wtb) {
    __shared__ float tile[64][65];
    const int g = blockIdx.x, t = threadIdx.x;
    if (g < 2560) {
        const float* src = (g < 2048) ? x : Wp;
        ushort* dst = (g < 2048) ? xb : wpb;
        int i = ((g < 2048) ? g : (g - 2048)) * 256 + t;
        const float4* s = reinterpret_cast<const float4*>(src);
        float4 a = s[2*i], b = s[2*i+1];
        union { ushort u[8]; int4 v; } r;
        r.u[0]=f2b(a.x); r.u[1]=f2b(a.y); r.u[2]=f2b(a.z); r.u[3]=f2b(a.w);
        r.u[4]=f2b(b.x); r.u[5]=f2b(b.y); r.u[6]=f2b(b.z); r.u[7]=f2b(b.w);
        reinterpret_cast<int4*>(dst)[i] = r.v;
        return;
    }
    const int gb = g - 2560;
    const int k0 = (gb & 15) * 64;
    const int math = gb >> 4;               // 0..47
    const int mat = math >> 4, h = math & 15;
    const float* W = (mat == 0 ? Wq : (mat == 1 ? Wk : Wv)) + (size_t)h * DM * HDIM;
#pragma unroll
    for (int it = 0; it < 4; ++it) {
        int row = it*16 + (t>>4), c4 = (t&15)*4;
        float4 v = *reinterpret_cast<const float4*>(&W[(size_t)(k0+row)*HDIM + c4]);
        tile[row][c4+0]=v.x; tile[row][c4+1]=v.y; tile[row][c4+2]=v.z; tile[row][c4+3]=v.w;
    }
    __syncthreads();
    ushort* out = wtb + (size_t)(mat*NH + h) * (HDIM*DM);
#pragma unroll
    for (int it = 0; it < 4; ++it) {
        int n = it*16 + (t>>4), kc = (t&15)*4;
        union { ushort u[4]; uint2 v; } r;
#pragma unroll
        for (int j = 0; j < 4; ++j) r.u[j] = f2b(tile[kc+j][n]);
        *reinterpret_cast<uint2*>(&out[(size_t)n*DM + k0 + kc]) = r.v;
    }
}

// ---------------------------------------------------------------------------
// m97-style GEMM: C[M][N] = A[M][1024] @ B[N][1024]^T
// 128x128 tile, BK=64, 4 waves, global_load_lds w16, XCD-chunked swizzle.
// EPI 0: qkv scatter (bf16, QSCALE on mat 0, all row-major [bh][t][e]).
// ---------------------------------------------------------------------------
template<int EPI>
__global__ __launch_bounds__(256) void gemm_bt(const ushort* __restrict__ A,
                                               const ushort* __restrict__ B,
                                               const float* __restrict__ bias,
                                               void* __restrict__ C) {
    __shared__ ushort As[128*64];
    __shared__ ushort Bs[128*64];
    const int tid = threadIdx.x;
    const int w = tid >> 6, l = tid & 63;
    const int lr = l & 15, lg = l >> 4;
    const int wr = (w >> 1) * 64, wc = (w & 1) * 64;
    const int cpx = (int)gridDim.x >> 3;
    const int wg = ((int)blockIdx.x & 7) * cpx + ((int)blockIdx.x >> 3);
    const int m0 = (wg & 31) * 128;
    const int n0 = (wg >> 5) * 128;
    const int srow = l >> 3;
    const int scol = (l & 7) * 8;

    f32x4 acc[4][4];
#pragma unroll
    for (int a = 0; a < 4; ++a)
#pragma unroll
        for (int b = 0; b < 4; ++b) acc[a][b] = {0.f, 0.f, 0.f, 0.f};

    for (int kc = 0; kc < DM/64; ++kc) {
        __syncthreads();
#pragma unroll
        for (int c = 0; c < 4; ++c) {
            int chunk = w*4 + c;
            int r = chunk*8 + srow;
            gload16(&A[(size_t)(m0+r)*DM + kc*64 + scol], &As[chunk*512]);
            gload16(&B[(size_t)(n0+r)*DM + kc*64 + scol], &Bs[chunk*512]);
        }
        __syncthreads();
#pragma unroll
        for (int kk = 0; kk < 2; ++kk) {
            bf16x8 af[4], bf[4];
#pragma unroll
            for (int mf = 0; mf < 4; ++mf)
                af[mf] = *reinterpret_cast<const bf16x8*>(&As[(wr + mf*16 + lr)*64 + kk*32 + lg*8]);
#pragma unroll
            for (int nf = 0; nf < 4; ++nf)
                bf[nf] = *reinterpret_cast<const bf16x8*>(&Bs[(wc + nf*16 + lr)*64 + kk*32 + lg*8]);
            __builtin_amdgcn_s_setprio(1);
#pragma unroll
            for (int mf = 0; mf < 4; ++mf)
#pragma unroll
                for (int nf = 0; nf < 4; ++nf)
                    acc[mf][nf] = __builtin_amdgcn_mfma_f32_16x16x32_bf16(
                        af[mf], bf[nf], acc[mf][nf], 0, 0, 0);
            __builtin_amdgcn_s_setprio(0);
        }
    }

    if (EPI == 0) {
        ushort* O = (ushort*)C;
#pragma unroll
        for (int mf = 0; mf < 4; ++mf) {
#pragma unroll
            for (int i = 0; i < 4; ++i) {
                int m = m0 + wr + mf*16 + lg*4 + i;
                int bq = m >> 11, t = m & (TSEQ - 1);
#pragma unroll
                for (int nf = 0; nf < 4; ++nf) {
                    int col = n0 + wc + nf*16 + lr;
                    int mat = col >> 10, hh = (col >> 6) & 15, e = col & 63;
                    float sc = (mat == 0) ? QSCALE : 1.0f;
                    O[((size_t)(mat*2*NH + bq*NH + hh))*(TSEQ*HDIM) + (size_t)t*HDIM + e] =
                        f2b(acc[mf][nf][i] * sc);
                }
            }
        }
    } else {
        float* O = (float*)C;
#pragma unroll
        for (int mf = 0; mf < 4; ++mf) {
#pragma unroll
            for (int i = 0; i < 4; ++i) {
                int m = m0 + wr + mf*16 + lg*4 + i;
#pragma unroll
                for (int nf = 0; nf < 4; ++nf) {
                    int col = n0 + wc + nf*16 + lr;
                    O[(size_t)m*DM + col] = acc[mf][nf][i] + bias[col];
                }
            }
        }
    }
}

// ---------------------------------------------------------------------------
// proj64: out = concat @ Wp^T + bias, 64x128 tiles -> 512 blocks = 2/CU
// (the 128x128 version was 256 blocks = 1 block/CU = latency-bound).
// 4 waves as 2x2; wave tile 32 rows x 64 cols (acc[2][4]). Linear LDS,
// global_load_lds w16, XCD-chunked swizzle.
// ---------------------------------------------------------------------------
__global__ __launch_bounds__(256) void proj64(const ushort* __restrict__ A,
                                              const ushort* __restrict__ B,
                                              const float* __restrict__ bias,
                                              float* __restrict__ O) {
    __shared__ ushort As[64*64];
    __shared__ ushort Bs[128*64];
    const int tid = threadIdx.x;
    const int w = tid >> 6, l = tid & 63;
    const int lr = l & 15, lg = l >> 4;
    const int wr = (w >> 1) * 32, wc = (w & 1) * 64;
    const int cpx = (int)gridDim.x >> 3;
    const int wg = ((int)blockIdx.x & 7) * cpx + ((int)blockIdx.x >> 3);
    const int m0 = (wg & 63) * 64;
    const int n0 = (wg >> 6) * 128;

    f32x4 acc[2][4];
#pragma unroll
    for (int a = 0; a < 2; ++a)
#pragma unroll
        for (int b = 0; b < 4; ++b) acc[a][b] = {0.f, 0.f, 0.f, 0.f};

    for (int kc = 0; kc < DM/64; ++kc) {
        __syncthreads();
        // A: 64 rows x 8 chunks = 512 chunks; thread covers tid, tid+256
#pragma unroll
        for (int it = 0; it < 2; ++it) {
            int u = it*256 + tid;
            int r = u >> 3, c = u & 7;
            gload16(&A[(size_t)(m0+r)*DM + kc*64 + c*8], &As[u*8]);
        }
        // B: 128 rows x 8 chunks = 1024 chunks; 4 per thread
#pragma unroll
        for (int it = 0; it < 4; ++it) {
            int u = it*256 + tid;
            int r = u >> 3, c = u & 7;
            gload16(&B[(size_t)(n0+r)*DM + kc*64 + c*8], &Bs[u*8]);
        }
        __syncthreads();
#pragma unroll
        for (int kk = 0; kk < 2; ++kk) {
            bf16x8 af[2], bf[4];
#pragma unroll
            for (int mf = 0; mf < 2; ++mf)
                af[mf] = *reinterpret_cast<const bf16x8*>(&As[(wr + mf*16 + lr)*64 + kk*32 + lg*8]);
#pragma unroll
            for (int nf = 0; nf < 4; ++nf)
                bf[nf] = *reinterpret_cast<const bf16x8*>(&Bs[(wc + nf*16 + lr)*64 + kk*32 + lg*8]);
            __builtin_amdgcn_s_setprio(1);
#pragma unroll
            for (int mf = 0; mf < 2; ++mf)
#pragma unroll
                for (int nf = 0; nf < 4; ++nf)
                    acc[mf][nf] = __builtin_amdgcn_mfma_f32_16x16x32_bf16(
                        af[mf], bf[nf], acc[mf][nf], 0, 0, 0);
            __builtin_amdgcn_s_setprio(0);
        }
    }
#pragma unroll
    for (int mf = 0; mf < 2; ++mf) {
#pragma unroll
        for (int i = 0; i < 4; ++i) {
            int m = m0 + wr + mf*16 + lg*4 + i;
#pragma unroll
            for (int nf = 0; nf < 4; ++nf) {
                int col = n0 + wc + nf*16 + lr;
                O[(size_t)m*DM + col] = acc[mf][nf][i] + bias[col];
            }
        }
    }
}

// ---------------------------------------------------------------------------
// Causal flash attention, paired q-tiles, 8-wave blocks. 512 blocks x 512 thr.
// Block (bh,p): q-tiles 16+p (waves 0-3), 15-p (waves 4-7); K/V staged once
// per block. Softmax: per-lane partial l (lg-group reduced ONCE at epilogue)
// and lazy cross-lane max (only when defer-max triggers). K: DMA XOR-swizzled;
// V: reg-staged transpose-scatter (loads early, writes after PV);
// P: cvt_pk -> per-wave LDS.
// ---------------------------------------------------------------------------
__global__ __launch_bounds__(512) void attn_mfma(const ushort* __restrict__ qkvb,
                                                 ushort* __restrict__ concatb) {
    __shared__ ushort Ks[2][64*64];
    __shared__ ushort Vt[2][64*64];     // [e][s], swizzled
    __shared__ ushort Ps[8][16*64];     // per-wave P^T (16 q-rows)
    const int tid = threadIdx.x;
    const int w = tid >> 6, l = tid & 63;
    const int lr = l & 15, lg = l >> 4;
    const int g = blockIdx.x;
    const int bh = (g & 7) * 4 + ((g >> 3) & 3);   // 4 heads per XCD
    const int p  = g >> 5;                          // pair index 0..15
    const int qtHI = 16 + p, qtLO = 15 - p;
    const int sub = w >> 2;                         // 0 = HI wave, 1 = LO wave
    const int ws  = w & 3;
    const int myqt = sub ? qtLO : qtHI;
    const int q0 = myqt * 64 + ws * 16;             // wave's 16 q-rows

    const ushort* Q = qkvb + (size_t)bh * (TSEQ*HDIM);
    const ushort* K = Q + (size_t)2*NH*TSEQ*HDIM;
    const ushort* V = K + (size_t)2*NH*TSEQ*HDIM;

    bf16x8 qf[2];
#pragma unroll
    for (int kk = 0; kk < 2; ++kk)
        qf[kk] = *reinterpret_cast<const bf16x8*>(&Q[(size_t)(q0 + lr)*HDIM + kk*32 + lg*8]);

    f32x4 acc[4];
    float mrow = -3e38f, lrow = 0.f;                // lrow = per-lane partial
#pragma unroll
    for (int nf = 0; nf < 4; ++nf) acc[nf] = {0.f, 0.f, 0.f, 0.f};

    ushort* PsW = &Ps[w][0];
    const int krow = tid >> 3;                      // 0..63 over 512 threads
    const int kchunk = (tid & 7) ^ ((tid >> 3) & 7);

    // ---- prologue: stage tile 0 into buf 0 (one pass, 512 threads) ----
    {
        gload16(&K[(size_t)krow*HDIM + kchunk*8], &Ks[0][tid*8]);
        BF8 a;
        a.v = *reinterpret_cast<const bf16x8*>(&V[(size_t)l*HDIM + w*8]);
#pragma unroll
        for (int j = 0; j < 8; ++j)
            Vt[0][(w*8 + j)*64 + ((l>>3) ^ j)*8 + (l&7)] = a.u[j];
        __syncthreads();
    }

    int cur = 0;
    for (int jt = 0; jt <= qtHI; ++jt) {
        const int nxt = cur ^ 1;
        const int s0 = jt * 64;
        const bool pref = (jt < qtHI);
        const bool active = (sub == 0) || (jt <= qtLO);
        BF8 ga;
        if (pref) {
            const int s0n = s0 + 64;
            gload16(&K[(size_t)(s0n + krow)*HDIM + kchunk*8], &Ks[nxt][tid*8]);
            ga.v = *reinterpret_cast<const bf16x8*>(&V[(size_t)(s0n + l)*HDIM + w*8]);
        }

        if (active) {
            // ---- QK^T ----
            f32x4 sT[4];
#pragma unroll
            for (int nf = 0; nf < 4; ++nf) sT[nf] = {0.f, 0.f, 0.f, 0.f};
#pragma unroll
            for (int kk = 0; kk < 2; ++kk) {
                bf16x8 kf[4];
#pragma unroll
                for (int nf = 0; nf < 4; ++nf)
                    kf[nf] = *reinterpret_cast<const bf16x8*>(
                        &Ks[cur][(nf*16 + lr)*64 + ((kk*4 + lg) ^ (lr&7))*8]);
                __builtin_amdgcn_s_setprio(1);
#pragma unroll
                for (int nf = 0; nf < 4; ++nf)
                    sT[nf] = __builtin_amdgcn_mfma_f32_16x16x32_bf16(kf[nf], qf[kk], sT[nf], 0, 0, 0);
                __builtin_amdgcn_s_setprio(0);
            }
            // causal mask on own diagonal tile
            if (jt == myqt) {
                int qrow = q0 + lr;
#pragma unroll
                for (int nf = 0; nf < 4; ++nf) {
                    int kbase = s0 + nf*16 + lg*4;
#pragma unroll
                    for (int i = 0; i < 4; ++i)
                        if (kbase + i > qrow) sT[nf][i] = -1e30f;
                }
            }
            // ---- per-lane online softmax; lazy cross-lane max; no sum shfl ----
            float g0 = fmax3(sT[0][0], sT[0][1], sT[0][2]);
            float g1 = fmax3(sT[0][3], sT[1][0], sT[1][1]);
            float g2 = fmax3(sT[1][2], sT[1][3], sT[2][0]);
            float g3 = fmax3(sT[2][1], sT[2][2], sT[2][3]);
            float g4 = fmax3(sT[3][0], sT[3][1], sT[3][2]);
            float tm = fmaxf(fmax3(fmax3(g0, g1, g2), g3, g4), sT[3][3]);
            if (__any(tm > mrow + 8.0f)) {          // rare after tile 0
                tm = fmaxf(tm, __shfl_xor(tm, 16, 64));
                tm = fmaxf(tm, __shfl_xor(tm, 32, 64));
                float mnew = fmaxf(mrow, tm);
                float corr = exp2f(mrow - mnew);
                lrow *= corr;
#pragma unroll
                for (int nf = 0; nf < 4; ++nf)
#pragma unroll
                    for (int i = 0; i < 4; ++i) acc[nf][i] *= corr;
                mrow = mnew;
            }
            float ps = 0.f;
#pragma unroll
            for (int nf = 0; nf < 4; ++nf)
#pragma unroll
                for (int i = 0; i < 4; ++i) { sT[nf][i] = exp2f(sT[nf][i] - mrow); ps += sT[nf][i]; }
            lrow += ps;                             // per-lane partial; reduce at end
            // P^T -> per-wave LDS (swizzled b64 writes)
#pragma unroll
            for (int nf = 0; nf < 4; ++nf) {
                uint2 pk;
                pk.x = cvtpk(sT[nf][0], sT[nf][1]);
                pk.y = cvtpk(sT[nf][2], sT[nf][3]);
                *reinterpret_cast<uint2*>(
                    &PsW[lr*64 + ((2*nf + (lg>>1)) ^ (lr&7))*8 + (lg&1)*4]) = pk;
            }
            // ---- PV ----
#pragma unroll
            for (int kk = 0; kk < 2; ++kk) {
                bf16x8 vf[4];
#pragma unroll
                for (int nf = 0; nf < 4; ++nf)
                    vf[nf] = *reinterpret_cast<const bf16x8*>(
                        &Vt[cur][(nf*16 + lr)*64 + ((kk*4 + lg) ^ (lr&7))*8]);
                bf16x8 pf = *reinterpret_cast<const bf16x8*>(
                    &PsW[lr*64 + ((kk*4 + lg) ^ (lr&7))*8]);
                __builtin_amdgcn_s_setprio(1);
#pragma unroll
                for (int nf = 0; nf < 4; ++nf)
                    acc[nf] = __builtin_amdgcn_mfma_f32_16x16x32_bf16(vf[nf], pf, acc[nf], 0, 0, 0);
                __builtin_amdgcn_s_setprio(0);
            }
        }

        // ---- finish staging next tile's V (loads issued at top) ----
        if (pref) {
#pragma unroll
            for (int j = 0; j < 8; ++j)
                Vt[nxt][(w*8 + j)*64 + ((l>>3) ^ j)*8 + (l&7)] = ga.u[j];
        }
        __syncthreads();
        cur = nxt;
    }

    // ---- epilogue: reduce per-lane l across the lg group (once), write O ----
    lrow += __shfl_xor(lrow, 16, 64);
    lrow += __shfl_xor(lrow, 32, 64);
    const int b = bh >> 4, h = bh & 15;
    {
        float inv = 1.0f / lrow;
        int t = q0 + lr;
        ushort* o = concatb + ((size_t)(b*TSEQ + t))*DM + h*HDIM;
#pragma unroll
        for (int nf = 0; nf < 4; ++nf) {
            uint2 pk;
            pk.x = cvtpk(acc[nf][0]*inv, acc[nf][1]*inv);
            pk.y = cvtpk(acc[nf][2]*inv, acc[nf][3]*inv);
            *reinterpret_cast<uint2*>(&o[nf*16 + lg*4]) = pk;
        }
    }
}

// ---------------------------------------------------------------------------
extern "C" void kernel_launch(void* const* d_in, const int* in_sizes, int n_in,
                              void* d_out, int out_size, void* d_ws, size_t ws_size,
                              hipStream_t stream) {
    const float* x  = (const float*)d_in[0];
    const float* Wq = (const float*)d_in[1];
    const float* Wk = (const float*)d_in[2];
    const float* Wv = (const float*)d_in[3];
    const float* Wp = (const float*)d_in[4];
    const float* bp = (const float*)d_in[5];
    float* out = (float*)d_out;

    ushort* ws   = (ushort*)d_ws;
    ushort* xb   = ws;                                    // BT*DM
    ushort* wtb  = xb  + (size_t)BT*DM;                   // [3072][1024]
    ushort* wpb  = wtb + (size_t)3*NH*HDIM*DM;            // DM*DM
    ushort* qkvb = wpb + (size_t)DM*DM;                   // [3][B*H][T][HD] row-major
    ushort* cb   = qkvb + (size_t)3*2*NH*TSEQ*HDIM;       // BT*DM

    prep_kernel<<<dim3(3328), 256, 0, stream>>>(x, Wq, Wk, Wv, Wp, xb, wpb, wtb);
    gemm_bt<0><<<dim3(32*24), 256, 0, stream>>>(xb, wtb, nullptr, qkvb);
    attn_mfma<<<dim3(512), 512, 0, stream>>>(qkvb, cb);
    proj64<<<dim3(64*8), 256, 0, stream>>>(cb, wpb, bp, out);
}

// Round 20
// 113.141 us; speedup vs baseline: 1.2240x; 1.0297x over previous
//
#include <hip/hip_runtime.h>
#include <hip/hip_bf16.h>

#define TSEQ 2048
#define DM   1024
#define NH   16
#define HDIM 64
#define NB   2
#define BT   (NB*TSEQ)   // 4096
// Q pre-scale: HD^-0.5 * log2(e) so softmax runs in exp2 domain
#define QSCALE 0.1803368801111204f

typedef __attribute__((ext_vector_type(8))) short bf16x8;
typedef __attribute__((ext_vector_type(4))) float f32x4;

union BF8 { bf16x8 v; ushort u[8]; };

static __device__ __forceinline__ ushort f2b(float x) {
    unsigned u = __float_as_uint(x);
    return (ushort)((u + 0x7fff + ((u >> 16) & 1)) >> 16);  // RNE, finite inputs
}

static __device__ __forceinline__ unsigned cvtpk(float lo, float hi) {
    unsigned r;
    asm("v_cvt_pk_bf16_f32 %0, %1, %2" : "=v"(r) : "v"(lo), "v"(hi));
    return r;
}

static __device__ __forceinline__ float fmax3(float a, float b, float c) {
    return fmaxf(fmaxf(a, b), c);   // clang fuses to v_max3_f32
}

static __device__ __forceinline__ void gload16(const void* g, void* l) {
    __builtin_amdgcn_global_load_lds((const __attribute__((address_space(1))) void*)g,
                                     (__attribute__((address_space(3))) void*)l, 16, 0, 0);
}

// ---------------------------------------------------------------------------
// Merged prep: [0,2048) cvt x -> bf16; [2048,2560) cvt Wp -> bf16;
// [2560,3328) per-head weight transpose f32 [D][HD] -> bf16 [mat][h][e][D].
// ---------------------------------------------------------------------------
__global__ __launch_bounds__(256) void prep_kernel(const float* __restrict__ x,
                                                   const float* __restrict__ Wq,
                                                   const float* __restrict__ Wk,
                                                   const float* __restrict__ Wv,
                                                   const float* __restrict__ Wp,
                                                   ushort* __restrict__ xb,
                                                   ushort* __restrict__ wpb,
                                                   ushort* __restrict__ wtb) {
    __shared__ float tile[64][65];
    const int g = blockIdx.x, t = threadIdx.x;
    if (g < 2560) {
        const float* src = (g < 2048) ? x : Wp;
        ushort* dst = (g < 2048) ? xb : wpb;
        int i = ((g < 2048) ? g : (g - 2048)) * 256 + t;
        const float4* s = reinterpret_cast<const float4*>(src);
        float4 a = s[2*i], b = s[2*i+1];
        union { ushort u[8]; int4 v; } r;
        r.u[0]=f2b(a.x); r.u[1]=f2b(a.y); r.u[2]=f2b(a.z); r.u[3]=f2b(a.w);
        r.u[4]=f2b(b.x); r.u[5]=f2b(b.y); r.u[6]=f2b(b.z); r.u[7]=f2b(b.w);
        reinterpret_cast<int4*>(dst)[i] = r.v;
        return;
    }
    const int gb = g - 2560;
    const int k0 = (gb & 15) * 64;
    const int math = gb >> 4;               // 0..47
    const int mat = math >> 4, h = math & 15;
    const float* W = (mat == 0 ? Wq : (mat == 1 ? Wk : Wv)) + (size_t)h * DM * HDIM;
#pragma unroll
    for (int it = 0; it < 4; ++it) {
        int row = it*16 + (t>>4), c4 = (t&15)*4;
        float4 v = *reinterpret_cast<const float4*>(&W[(size_t)(k0+row)*HDIM + c4]);
        tile[row][c4+0]=v.x; tile[row][c4+1]=v.y; tile[row][c4+2]=v.z; tile[row][c4+3]=v.w;
    }
    __syncthreads();
    ushort* out = wtb + (size_t)(mat*NH + h) * (HDIM*DM);
#pragma unroll
    for (int it = 0; it < 4; ++it) {
        int n = it*16 + (t>>4), kc = (t&15)*4;
        union { ushort u[4]; uint2 v; } r;
#pragma unroll
        for (int j = 0; j < 4; ++j) r.u[j] = f2b(tile[kc+j][n]);
        *reinterpret_cast<uint2*>(&out[(size_t)n*DM + k0 + kc]) = r.v;
    }
}

// ---------------------------------------------------------------------------
// m97-style GEMM: C[M][N] = A[M][1024] @ B[N][1024]^T
// 128x128 tile, BK=64, 4 waves, global_load_lds w16, XCD-chunked swizzle.
// EPI 0: qkv scatter (bf16, QSCALE on mat 0, all row-major [bh][t][e]).
// ---------------------------------------------------------------------------
template<int EPI>
__global__ __launch_bounds__(256) void gemm_bt(const ushort* __restrict__ A,
                                               const ushort* __restrict__ B,
                                               const float* __restrict__ bias,
                                               void* __restrict__ C) {
    __shared__ ushort As[128*64];
    __shared__ ushort Bs[128*64];
    const int tid = threadIdx.x;
    const int w = tid >> 6, l = tid & 63;
    const int lr = l & 15, lg = l >> 4;
    const int wr = (w >> 1) * 64, wc = (w & 1) * 64;
    const int cpx = (int)gridDim.x >> 3;
    const int wg = ((int)blockIdx.x & 7) * cpx + ((int)blockIdx.x >> 3);
    const int m0 = (wg & 31) * 128;
    const int n0 = (wg >> 5) * 128;
    const int srow = l >> 3;
    const int scol = (l & 7) * 8;

    f32x4 acc[4][4];
#pragma unroll
    for (int a = 0; a < 4; ++a)
#pragma unroll
        for (int b = 0; b < 4; ++b) acc[a][b] = {0.f, 0.f, 0.f, 0.f};

    for (int kc = 0; kc < DM/64; ++kc) {
        __syncthreads();
#pragma unroll
        for (int c = 0; c < 4; ++c) {
            int chunk = w*4 + c;
            int r = chunk*8 + srow;
            gload16(&A[(size_t)(m0+r)*DM + kc*64 + scol], &As[chunk*512]);
            gload16(&B[(size_t)(n0+r)*DM + kc*64 + scol], &Bs[chunk*512]);
        }
        __syncthreads();
#pragma unroll
        for (int kk = 0; kk < 2; ++kk) {
            bf16x8 af[4], bf[4];
#pragma unroll
            for (int mf = 0; mf < 4; ++mf)
                af[mf] = *reinterpret_cast<const bf16x8*>(&As[(wr + mf*16 + lr)*64 + kk*32 + lg*8]);
#pragma unroll
            for (int nf = 0; nf < 4; ++nf)
                bf[nf] = *reinterpret_cast<const bf16x8*>(&Bs[(wc + nf*16 + lr)*64 + kk*32 + lg*8]);
            __builtin_amdgcn_s_setprio(1);
#pragma unroll
            for (int mf = 0; mf < 4; ++mf)
#pragma unroll
                for (int nf = 0; nf < 4; ++nf)
                    acc[mf][nf] = __builtin_amdgcn_mfma_f32_16x16x32_bf16(
                        af[mf], bf[nf], acc[mf][nf], 0, 0, 0);
            __builtin_amdgcn_s_setprio(0);
        }
    }

    if (EPI == 0) {
        ushort* O = (ushort*)C;
#pragma unroll
        for (int mf = 0; mf < 4; ++mf) {
#pragma unroll
            for (int i = 0; i < 4; ++i) {
                int m = m0 + wr + mf*16 + lg*4 + i;
                int bq = m >> 11, t = m & (TSEQ - 1);
#pragma unroll
                for (int nf = 0; nf < 4; ++nf) {
                    int col = n0 + wc + nf*16 + lr;
                    int mat = col >> 10, hh = (col >> 6) & 15, e = col & 63;
                    float sc = (mat == 0) ? QSCALE : 1.0f;
                    O[((size_t)(mat*2*NH + bq*NH + hh))*(TSEQ*HDIM) + (size_t)t*HDIM + e] =
                        f2b(acc[mf][nf][i] * sc);
                }
            }
        }
    } else {
        float* O = (float*)C;
#pragma unroll
        for (int mf = 0; mf < 4; ++mf) {
#pragma unroll
            for (int i = 0; i < 4; ++i) {
                int m = m0 + wr + mf*16 + lg*4 + i;
#pragma unroll
                for (int nf = 0; nf < 4; ++nf) {
                    int col = n0 + wc + nf*16 + lr;
                    O[(size_t)m*DM + col] = acc[mf][nf][i] + bias[col];
                }
            }
        }
    }
}

// ---------------------------------------------------------------------------
// proj64: out = concat @ Wp^T + bias, 64x128 tiles -> 512 blocks = 2/CU.
// 4 waves as 2x2; wave tile 32 rows x 64 cols (acc[2][4]). Linear LDS,
// global_load_lds w16, XCD-chunked swizzle.
// ---------------------------------------------------------------------------
__global__ __launch_bounds__(256) void proj64(const ushort* __restrict__ A,
                                              const ushort* __restrict__ B,
                                              const float* __restrict__ bias,
                                              float* __restrict__ O) {
    __shared__ ushort As[64*64];
    __shared__ ushort Bs[128*64];
    const int tid = threadIdx.x;
    const int w = tid >> 6, l = tid & 63;
    const int lr = l & 15, lg = l >> 4;
    const int wr = (w >> 1) * 32, wc = (w & 1) * 64;
    const int cpx = (int)gridDim.x >> 3;
    const int wg = ((int)blockIdx.x & 7) * cpx + ((int)blockIdx.x >> 3);
    const int m0 = (wg & 63) * 64;
    const int n0 = (wg >> 6) * 128;

    f32x4 acc[2][4];
#pragma unroll
    for (int a = 0; a < 2; ++a)
#pragma unroll
        for (int b = 0; b < 4; ++b) acc[a][b] = {0.f, 0.f, 0.f, 0.f};

    for (int kc = 0; kc < DM/64; ++kc) {
        __syncthreads();
#pragma unroll
        for (int it = 0; it < 2; ++it) {
            int u = it*256 + tid;
            int r = u >> 3, c = u & 7;
            gload16(&A[(size_t)(m0+r)*DM + kc*64 + c*8], &As[u*8]);
        }
#pragma unroll
        for (int it = 0; it < 4; ++it) {
            int u = it*256 + tid;
            int r = u >> 3, c = u & 7;
            gload16(&B[(size_t)(n0+r)*DM + kc*64 + c*8], &Bs[u*8]);
        }
        __syncthreads();
#pragma unroll
        for (int kk = 0; kk < 2; ++kk) {
            bf16x8 af[2], bf[4];
#pragma unroll
            for (int mf = 0; mf < 2; ++mf)
                af[mf] = *reinterpret_cast<const bf16x8*>(&As[(wr + mf*16 + lr)*64 + kk*32 + lg*8]);
#pragma unroll
            for (int nf = 0; nf < 4; ++nf)
                bf[nf] = *reinterpret_cast<const bf16x8*>(&Bs[(wc + nf*16 + lr)*64 + kk*32 + lg*8]);
            __builtin_amdgcn_s_setprio(1);
#pragma unroll
            for (int mf = 0; mf < 2; ++mf)
#pragma unroll
                for (int nf = 0; nf < 4; ++nf)
                    acc[mf][nf] = __builtin_amdgcn_mfma_f32_16x16x32_bf16(
                        af[mf], bf[nf], acc[mf][nf], 0, 0, 0);
            __builtin_amdgcn_s_setprio(0);
        }
    }
#pragma unroll
    for (int mf = 0; mf < 2; ++mf) {
#pragma unroll
        for (int i = 0; i < 4; ++i) {
            int m = m0 + wr + mf*16 + lg*4 + i;
#pragma unroll
            for (int nf = 0; nf < 4; ++nf) {
                int col = n0 + wc + nf*16 + lr;
                O[(size_t)m*DM + col] = acc[mf][nf][i] + bias[col];
            }
        }
    }
}

// ---------------------------------------------------------------------------
// Causal flash attention, paired q-tiles, 8-wave blocks. 512 blocks x 512 thr.
// Block (bh,p): q-tiles 16+p (waves 0-3), 15-p (waves 4-7); K/V staged once
// per block. BALANCED-PAIR dispatch decode: first 256 blocks carry
// p = 15-(g>>5) (largest first = LPT under dynamic backfill), second 256
// carry p = (g-256)>>5 -> under static round-robin (CU c gets g=c, c+256)
// every CU's two blocks sum to a constant 49 iterations (was 42+2p, 33%
// spread). Softmax: per-lane partial l + lazy cross-lane max. K: DMA
// XOR-swizzled; V: reg-staged transpose-scatter; P: cvt_pk -> per-wave LDS.
// ---------------------------------------------------------------------------
__global__ __launch_bounds__(512) void attn_mfma(const ushort* __restrict__ qkvb,
                                                 ushort* __restrict__ concatb) {
    __shared__ ushort Ks[2][64*64];
    __shared__ ushort Vt[2][64*64];     // [e][s], swizzled
    __shared__ ushort Ps[8][16*64];     // per-wave P^T (16 q-rows)
    const int tid = threadIdx.x;
    const int w = tid >> 6, l = tid & 63;
    const int lr = l & 15, lg = l >> 4;
    const int g = blockIdx.x;
    const int gl = g & 255;
    const int bh = (gl & 7) * 4 + ((gl >> 3) & 3);  // 4 heads per XCD
    const int p  = (g < 256) ? (15 - (gl >> 5)) : (gl >> 5);  // balanced pairs
    const int qtHI = 16 + p, qtLO = 15 - p;
    const int sub = w >> 2;                         // 0 = HI wave, 1 = LO wave
    const int ws  = w & 3;
    const int myqt = sub ? qtLO : qtHI;
    const int q0 = myqt * 64 + ws * 16;             // wave's 16 q-rows

    const ushort* Q = qkvb + (size_t)bh * (TSEQ*HDIM);
    const ushort* K = Q + (size_t)2*NH*TSEQ*HDIM;
    const ushort* V = K + (size_t)2*NH*TSEQ*HDIM;

    bf16x8 qf[2];
#pragma unroll
    for (int kk = 0; kk < 2; ++kk)
        qf[kk] = *reinterpret_cast<const bf16x8*>(&Q[(size_t)(q0 + lr)*HDIM + kk*32 + lg*8]);

    f32x4 acc[4];
    float mrow = -3e38f, lrow = 0.f;                // lrow = per-lane partial
#pragma unroll
    for (int nf = 0; nf < 4; ++nf) acc[nf] = {0.f, 0.f, 0.f, 0.f};

    ushort* PsW = &Ps[w][0];
    const int krow = tid >> 3;                      // 0..63 over 512 threads
    const int kchunk = (tid & 7) ^ ((tid >> 3) & 7);

    // ---- prologue: stage tile 0 into buf 0 (one pass, 512 threads) ----
    {
        gload16(&K[(size_t)krow*HDIM + kchunk*8], &Ks[0][tid*8]);
        BF8 a;
        a.v = *reinterpret_cast<const bf16x8*>(&V[(size_t)l*HDIM + w*8]);
#pragma unroll
        for (int j = 0; j < 8; ++j)
            Vt[0][(w*8 + j)*64 + ((l>>3) ^ j)*8 + (l&7)] = a.u[j];
        __syncthreads();
    }

    int cur = 0;
    for (int jt = 0; jt <= qtHI; ++jt) {
        const int nxt = cur ^ 1;
        const int s0 = jt * 64;
        const bool pref = (jt < qtHI);
        const bool active = (sub == 0) || (jt <= qtLO);
        BF8 ga;
        if (pref) {
            const int s0n = s0 + 64;
            gload16(&K[(size_t)(s0n + krow)*HDIM + kchunk*8], &Ks[nxt][tid*8]);
            ga.v = *reinterpret_cast<const bf16x8*>(&V[(size_t)(s0n + l)*HDIM + w*8]);
        }

        if (active) {
            // ---- QK^T ----
            f32x4 sT[4];
#pragma unroll
            for (int nf = 0; nf < 4; ++nf) sT[nf] = {0.f, 0.f, 0.f, 0.f};
#pragma unroll
            for (int kk = 0; kk < 2; ++kk) {
                bf16x8 kf[4];
#pragma unroll
                for (int nf = 0; nf < 4; ++nf)
                    kf[nf] = *reinterpret_cast<const bf16x8*>(
                        &Ks[cur][(nf*16 + lr)*64 + ((kk*4 + lg) ^ (lr&7))*8]);
                __builtin_amdgcn_s_setprio(1);
#pragma unroll
                for (int nf = 0; nf < 4; ++nf)
                    sT[nf] = __builtin_amdgcn_mfma_f32_16x16x32_bf16(kf[nf], qf[kk], sT[nf], 0, 0, 0);
                __builtin_amdgcn_s_setprio(0);
            }
            // causal mask on own diagonal tile
            if (jt == myqt) {
                int qrow = q0 + lr;
#pragma unroll
                for (int nf = 0; nf < 4; ++nf) {
                    int kbase = s0 + nf*16 + lg*4;
#pragma unroll
                    for (int i = 0; i < 4; ++i)
                        if (kbase + i > qrow) sT[nf][i] = -1e30f;
                }
            }
            // ---- per-lane online softmax; lazy cross-lane max; no sum shfl ----
            float g0 = fmax3(sT[0][0], sT[0][1], sT[0][2]);
            float g1 = fmax3(sT[0][3], sT[1][0], sT[1][1]);
            float g2 = fmax3(sT[1][2], sT[1][3], sT[2][0]);
            float g3 = fmax3(sT[2][1], sT[2][2], sT[2][3]);
            float g4 = fmax3(sT[3][0], sT[3][1], sT[3][2]);
            float tm = fmaxf(fmax3(fmax3(g0, g1, g2), g3, g4), sT[3][3]);
            if (__any(tm > mrow + 8.0f)) {          // rare after tile 0
                tm = fmaxf(tm, __shfl_xor(tm, 16, 64));
                tm = fmaxf(tm, __shfl_xor(tm, 32, 64));
                float mnew = fmaxf(mrow, tm);
                float corr = exp2f(mrow - mnew);
                lrow *= corr;
#pragma unroll
                for (int nf = 0; nf < 4; ++nf)
#pragma unroll
                    for (int i = 0; i < 4; ++i) acc[nf][i] *= corr;
                mrow = mnew;
            }
            float ps = 0.f;
#pragma unroll
            for (int nf = 0; nf < 4; ++nf)
#pragma unroll
                for (int i = 0; i < 4; ++i) { sT[nf][i] = exp2f(sT[nf][i] - mrow); ps += sT[nf][i]; }
            lrow += ps;                             // per-lane partial; reduce at end
            // P^T -> per-wave LDS (swizzled b64 writes)
#pragma unroll
            for (int nf = 0; nf < 4; ++nf) {
                uint2 pk;
                pk.x = cvtpk(sT[nf][0], sT[nf][1]);
                pk.y = cvtpk(sT[nf][2], sT[nf][3]);
                *reinterpret_cast<uint2*>(
                    &PsW[lr*64 + ((2*nf + (lg>>1)) ^ (lr&7))*8 + (lg&1)*4]) = pk;
            }
            // ---- PV ----
#pragma unroll
            for (int kk = 0; kk < 2; ++kk) {
                bf16x8 vf[4];
#pragma unroll
                for (int nf = 0; nf < 4; ++nf)
                    vf[nf] = *reinterpret_cast<const bf16x8*>(
                        &Vt[cur][(nf*16 + lr)*64 + ((kk*4 + lg) ^ (lr&7))*8]);
                bf16x8 pf = *reinterpret_cast<const bf16x8*>(
                    &PsW[lr*64 + ((kk*4 + lg) ^ (lr&7))*8]);
                __builtin_amdgcn_s_setprio(1);
#pragma unroll
                for (int nf = 0; nf < 4; ++nf)
                    acc[nf] = __builtin_amdgcn_mfma_f32_16x16x32_bf16(vf[nf], pf, acc[nf], 0, 0, 0);
                __builtin_amdgcn_s_setprio(0);
            }
        }

        // ---- finish staging next tile's V (loads issued at top) ----
        if (pref) {
#pragma unroll
            for (int j = 0; j < 8; ++j)
                Vt[nxt][(w*8 + j)*64 + ((l>>3) ^ j)*8 + (l&7)] = ga.u[j];
        }
        __syncthreads();
        cur = nxt;
    }

    // ---- epilogue: reduce per-lane l across the lg group (once), write O ----
    lrow += __shfl_xor(lrow, 16, 64);
    lrow += __shfl_xor(lrow, 32, 64);
    const int b = bh >> 4, h = bh & 15;
    {
        float inv = 1.0f / lrow;
        int t = q0 + lr;
        ushort* o = concatb + ((size_t)(b*TSEQ + t))*DM + h*HDIM;
#pragma unroll
        for (int nf = 0; nf < 4; ++nf) {
            uint2 pk;
            pk.x = cvtpk(acc[nf][0]*inv, acc[nf][1]*inv);
            pk.y = cvtpk(acc[nf][2]*inv, acc[nf][3]*inv);
            *reinterpret_cast<uint2*>(&o[nf*16 + lg*4]) = pk;
        }
    }
}

// ---------------------------------------------------------------------------
extern "C" void kernel_launch(void* const* d_in, const int* in_sizes, int n_in,
                              void* d_out, int out_size, void* d_ws, size_t ws_size,
                              hipStream_t stream) {
    const float* x  = (const float*)d_in[0];
    const float* Wq = (const float*)d_in[1];
    const float* Wk = (const float*)d_in[2];
    const float* Wv = (const float*)d_in[3];
    const float* Wp = (const float*)d_in[4];
    const float* bp = (const float*)d_in[5];
    float* out = (float*)d_out;

    ushort* ws   = (ushort*)d_ws;
    ushort* xb   = ws;                                    // BT*DM
    ushort* wtb  = xb  + (size_t)BT*DM;                   // [3072][1024]
    ushort* wpb  = wtb + (size_t)3*NH*HDIM*DM;            // DM*DM
    ushort* qkvb = wpb + (size_t)DM*DM;                   // [3][B*H][T][HD] row-major
    ushort* cb   = qkvb + (size_t)3*2*NH*TSEQ*HDIM;       // BT*DM

    prep_kernel<<<dim3(3328), 256, 0, stream>>>(x, Wq, Wk, Wv, Wp, xb, wpb, wtb);
    gemm_bt<0><<<dim3(32*24), 256, 0, stream>>>(xb, wtb, nullptr, qkvb);
    attn_mfma<<<dim3(512), 512, 0, stream>>>(qkvb, cb);
    proj64<<<dim3(64*8), 256, 0, stream>>>(cb, wpb, bp, out);
}